// Round 1
// baseline (2289.697 us; speedup 1.0000x reference)
//
#include <hip/hip_runtime.h>
#include <stdint.h>
#include <stddef.h>

// FP8Linear == bias-GEMM: the reference's quant-dequant is an fp32 identity
// (no actual fp8 rounding; clip at +-448 never binds since scale=amax/448).
// So compute Y[M,N] = X[M,K] @ W[N,K]^T + bias[N] with fp16 MFMA.
// M=8192, N=16384, K=4096 here (derived from in_sizes at launch).

typedef _Float16 f16_t;
typedef _Float16 f16x8 __attribute__((ext_vector_type(8)));
typedef float    f32x4 __attribute__((ext_vector_type(4)));

#define BM 128
#define BN 128
#define BK 32

// ---------------- fp32 -> fp16 conversion (8 elems/thread) ----------------
__global__ void __launch_bounds__(256) cvt_f32_to_f16(const float* __restrict__ src,
                                                      f16_t* __restrict__ dst,
                                                      int n8) {
    int i = blockIdx.x * 256 + threadIdx.x;
    if (i >= n8) return;
    const float4* s = (const float4*)src;
    float4 a = s[2 * i + 0];
    float4 b = s[2 * i + 1];
    f16x8 r;
    r[0] = (f16_t)a.x; r[1] = (f16_t)a.y; r[2] = (f16_t)a.z; r[3] = (f16_t)a.w;
    r[4] = (f16_t)b.x; r[5] = (f16_t)b.y; r[6] = (f16_t)b.z; r[7] = (f16_t)b.w;
    *(f16x8*)(dst + (size_t)i * 8) = r;
}

// ------------- async global->LDS, 16B per lane, wave-uniform LDS base -------------
__device__ __forceinline__ void load_lds_16B(const f16_t* g, f16_t* l) {
    __builtin_amdgcn_global_load_lds(
        (const __attribute__((address_space(1))) void*)g,
        (__attribute__((address_space(3))) void*)l,
        16, 0, 0);
}

// ---------------- NT GEMM + bias epilogue (m97 structure) ----------------
// Block: 256 threads = 4 waves (2x2), each wave = 64x64 via 4x4 of 16x16x32 MFMA.
// LDS: As[128][32], Bs[128][32] fp16, row-major, unpadded (global_load_lds
// requires lane-contiguous LDS; ds_read_b128 fragments are 16B aligned).
__global__ void __launch_bounds__(256) gemm_bt_bias(const f16_t* __restrict__ A,
                                                    const f16_t* __restrict__ B,
                                                    const float* __restrict__ bias,
                                                    float* __restrict__ C,
                                                    int M, int N, int K) {
    __shared__ __align__(16) f16_t As[BM * BK];  // 8 KB
    __shared__ __align__(16) f16_t Bs[BN * BK];  // 8 KB

    const int tid  = threadIdx.x;
    const int wave = tid >> 6;            // 0..3
    const int lane = tid & 63;
    const int wm   = (wave >> 1) * 64;    // wave row offset in tile
    const int wn   = (wave & 1) * 64;     // wave col offset in tile
    const int bm   = blockIdx.y;
    const int bn   = blockIdx.x;

    // Staging: wave w loads rows [32w, 32w+32) of both tiles.
    // One global_load_lds: lane i -> row 32w + i/4, 16B chunk (i&3).
    // LDS byte offset = wavebase + i*16  (row stride 32 elems * 2B = 64B = 4 chunks).
    const int srow = (wave << 5) + (lane >> 2);   // 0..127
    const int scol = (lane & 3) << 3;             // 0,8,16,24 (elements)

    const f16_t* gA = A + (size_t)(bm * BM + srow) * K + scol;
    const f16_t* gB = B + (size_t)(bn * BN + srow) * K + scol;
    f16_t* lA = As + (wave << 5) * BK;
    f16_t* lB = Bs + (wave << 5) * BK;

    const int quad = lane >> 4;   // 0..3
    const int l16  = lane & 15;

    f32x4 acc[4][4];
#pragma unroll
    for (int i = 0; i < 4; ++i)
#pragma unroll
        for (int j = 0; j < 4; ++j)
            acc[i][j] = (f32x4){0.f, 0.f, 0.f, 0.f};

    for (int k0 = 0; k0 < K; k0 += BK) {
        // stage A-tile and B-tile (4 x 1KB per wave)
        load_lds_16B(gA, lA);
        load_lds_16B(gA + (size_t)16 * K, lA + 16 * BK);
        load_lds_16B(gB, lB);
        load_lds_16B(gB + (size_t)16 * K, lB + 16 * BK);
        gA += BK;
        gB += BK;
        __syncthreads();   // compiler drains vmcnt before s_barrier

        // LDS -> fragments: A[m=l16][k=quad*8+j], B[n=l16][k=quad*8+j]
        f16x8 af[4], bfr[4];
#pragma unroll
        for (int i = 0; i < 4; ++i)
            af[i] = *(const f16x8*)(As + (wm + i * 16 + l16) * BK + quad * 8);
#pragma unroll
        for (int j = 0; j < 4; ++j)
            bfr[j] = *(const f16x8*)(Bs + (wn + j * 16 + l16) * BK + quad * 8);

#pragma unroll
        for (int i = 0; i < 4; ++i)
#pragma unroll
            for (int j = 0; j < 4; ++j)
                acc[i][j] = __builtin_amdgcn_mfma_f32_16x16x32_f16(af[i], bfr[j],
                                                                   acc[i][j], 0, 0, 0);
        __syncthreads();
    }

    // Epilogue: C/D layout col=lane&15, row=quad*4+reg. Fuse bias.
#pragma unroll
    for (int j = 0; j < 4; ++j) {
        const int col = bn * BN + wn + j * 16 + l16;
        const float bv = bias[col];
#pragma unroll
        for (int i = 0; i < 4; ++i) {
            const int row0 = bm * BM + wm + i * 16 + quad * 4;
            float* cp = C + (size_t)row0 * N + col;
#pragma unroll
            for (int r = 0; r < 4; ++r)
                cp[(size_t)r * N] = acc[i][j][r] + bv;
        }
    }
}

extern "C" void kernel_launch(void* const* d_in, const int* in_sizes, int n_in,
                              void* d_out, int out_size, void* d_ws, size_t ws_size,
                              hipStream_t stream) {
    const float* X    = (const float*)d_in[0];   // [M,K] (B*S flattened)
    const float* W    = (const float*)d_in[1];   // [N,K]
    const float* bias = (const float*)d_in[2];   // [N]
    float* out        = (float*)d_out;           // [M,N]

    const int N = in_sizes[2];            // 16384
    const int K = in_sizes[1] / N;        // 4096
    const int M = in_sizes[0] / K;        // 8192

    // workspace: Xh (M*K fp16 = 64 MiB) then Wh (N*K fp16 = 128 MiB)
    f16_t* Xh = (f16_t*)d_ws;
    f16_t* Wh = Xh + (size_t)M * K;

    const int nx8 = (M * K) / 8;
    const int nw8 = (N * K) / 8;
    cvt_f32_to_f16<<<dim3((nx8 + 255) / 256), 256, 0, stream>>>(X, Xh, nx8);
    cvt_f32_to_f16<<<dim3((nw8 + 255) / 256), 256, 0, stream>>>(W, Wh, nw8);

    gemm_bt_bias<<<dim3(N / BN, M / BM), dim3(256), 0, stream>>>(Xh, Wh, bias, out,
                                                                 M, N, K);
}